// Round 2
// baseline (418.902 us; speedup 1.0000x reference)
//
#include <hip/hip_runtime.h>
#include <hip/hip_bf16.h>

#define C_IN 64
#define H_IN 512
#define W_IN 512
#define D_OUT 128
#define OH 510
#define OW 510

typedef __bf16 bf16x8 __attribute__((ext_vector_type(8)));
typedef float  f32x4  __attribute__((ext_vector_type(4)));
typedef float  f32x2  __attribute__((ext_vector_type(2)));

#define TIN_ELEMS (H_IN * W_IN * C_IN)
#define TIN_BYTES ((size_t)TIN_ELEMS * 2)        // 32 MB
#define WT_BYTES  (9 * D_OUT * C_IN * 2)         // 147,456
#define WS_NEEDED (TIN_BYTES + WT_BYTES)

// ---------- pre-pass: kernels [D][C][3][3] fp32 -> wt[kpos][d][c] bf16 ----------
__global__ void prep_weights(const float* __restrict__ w, __bf16* __restrict__ wt) {
    int i = blockIdx.x * blockDim.x + threadIdx.x;
    if (i >= 9 * D_OUT * C_IN) return;
    int c    = i & 63;
    int d    = (i >> 6) & 127;
    int kpos = i >> 13;
    wt[i] = (__bf16)w[((d * C_IN) + c) * 9 + kpos];
}

// ---------- pre-pass: input [c][y][x] fp32 -> tin[y][x][c] bf16 ----------
// Round 2: cc chunk moved into the grid (1024 -> 2048 blocks). With the loop,
// the kernel launched exactly its resident capacity (4 blocks/CU) -> no queue
// depth to hide the load->barrier->read serial chain. Now 8 blocks/CU queued.
__global__ __launch_bounds__(256, 4)
void transpose_in(const float* __restrict__ in, __bf16* __restrict__ tin) {
    __shared__ float ls[32 * 257];          // 32 c-rows, stride 257 dwords (bank-spread)
    const int b    = blockIdx.x;            // 2048
    const int y    = b >> 2;
    const int px0  = ((b >> 1) & 1) << 8;
    const int cc   = b & 1;
    const int t    = threadIdx.x;
    const int wave = t >> 6;
    const int lane = t & 63;

#pragma unroll
    for (int j = 0; j < 8; j++) {
        const int cl = wave * 8 + j;        // chunk-local c
        f32x4 v = *(const f32x4*)&in[(cc * 32 + cl) * (H_IN * W_IN) + y * W_IN + px0 + lane * 4];
        *(f32x4*)&ls[cl * 257 + lane * 4] = v;
    }
    __syncthreads();
    const int oct = t & 3;                  // c-octet within 32-chunk
    const int pxw = t >> 2;                 // 0..63
#pragma unroll
    for (int pass = 0; pass < 4; pass++) {
        const int pxl = pass * 64 + pxw;
        bf16x8 v;
#pragma unroll
        for (int j = 0; j < 8; j++)
            v[j] = (__bf16)ls[(oct * 8 + j) * 257 + pxl];
        *(bf16x8*)&tin[((size_t)(y * W_IN) + px0 + pxl) * C_IN + cc * 32 + oct * 8] = v;
    }
}

// ---------- main conv v4: 512-thread 2-row blocks + XCD-chunked swizzle ----------
// Round-2 restructure. v3 counters: MfmaUtil 7.8 / VALU 4.5 / HBM 22% / Occ 42%
// -> still latency-bound, capped by 256-thread blocks x 4-block LDS limit
// (16 waves/CU) and by tin loads missing L2 (dt-split re-reads tin 4x from 8
// different XCDs; FETCH grew 117->215 MB). Fixes:
//  (a) block = 2 output rows x 256 px x 32 d, 8 waves. Same 36,864 B weight
//      slab amortized over 2 rows; 3 blocks/CU (launch_bounds 512,6) = 24
//      waves/CU, 1.8x the concurrency.
//  (b) bijective XCD-chunked blockIdx swizzle (grid 2040 % 8 == 0): all 8
//      (xt,dt) blocks sharing tin rows land on one XCD -> tin L2-resident.
#define BPX 256
#define LO_STRIDE 260                        // dwords; 16B-aligned rows, bank-spread

__global__ __launch_bounds__(512, 6)
void conv_main(const __bf16* __restrict__ tin, const __bf16* __restrict__ wt,
               const float* __restrict__ bias, float* __restrict__ out) {
    __shared__ __align__(16) char smem[9 * 32 * 64 * 2];   // 36,864 B
    __bf16* lw = (__bf16*)smem;              // [9][32][64] bf16, swizzled
    float*  lo = (float*)smem;               // [32][260] f32 (33,280 B) after main loop

    // XCD-chunked swizzle: bid%8 picks the XCD (round-robin dispatch), so give
    // each XCD one contiguous y2 chunk. 2040/8 = 255 exactly -> bijective.
    const int bid = blockIdx.x;
    const int swz = (bid & 7) * 255 + (bid >> 3);
    const int dt  = swz & 3;
    const int xt  = (swz >> 2) & 1;
    const int y   = (swz >> 3) << 1;         // 0,2,...,508
    const int d0  = dt << 5;
    const int x0  = xt ? (OW - BPX) : 0;     // 0 or 254 (overlap px recomputed, same values)

    const int t    = threadIdx.x;
    const int wave = t >> 6;                 // 0..7
    const int lane = t & 63;
    const int l15  = lane & 15;
    const int quad = lane >> 4;
    const int wr   = wave >> 2;              // row within block (0/1)
    const int wp   = wave & 3;               // 64-px group within row

    // ---- stage this block's 32-d weight slice into LDS (once, all 9 kpos) ----
    for (int u = t; u < 9 * 32 * 8; u += 512) {
        const int kpos = u >> 8;
        const int r    = u & 255;
        const int dl   = r >> 3;
        const int oc   = r & 7;
        const int ocs  = (oc ^ (dl & 7)) * 8;   // XOR-swizzle 16B units within row
        bf16x8 v = *(const bf16x8*)(wt + kpos * (D_OUT * C_IN) + (d0 + dl) * C_IN + oc * 8);
        *(bf16x8*)&lw[(kpos * 32 + dl) * 64 + ocs] = v;
    }
    __syncthreads();

    // ---- main loop: wave covers row y+wr, px = x0 + wp*64 + [0,64), d = d0+[0,32) ----
    f32x4 acc[4][2];
#pragma unroll
    for (int pxg = 0; pxg < 4; pxg++)
#pragma unroll
        for (int dg = 0; dg < 2; dg++)
            acc[pxg][dg] = (f32x4){0.f, 0.f, 0.f, 0.f};

    const __bf16* tb = tin + ((size_t)(y + wr) * W_IN + x0 + wp * 64) * C_IN + quad * 8;
#pragma unroll
    for (int kpos = 0; kpos < 9; kpos++) {
        const int ky = kpos / 3, kx = kpos % 3;
#pragma unroll
        for (int ch = 0; ch < 2; ch++) {
            const int us = (((ch * 4 + quad) ^ (l15 & 7)) * 8);   // swizzled c-unit
            bf16x8 w0 = *(const bf16x8*)&lw[(kpos * 32 + l15) * 64 + us];
            bf16x8 w1 = *(const bf16x8*)&lw[(kpos * 32 + 16 + l15) * 64 + us];
            const __bf16* base = tb + ((size_t)ky * W_IN + kx) * C_IN + ch * 32;
#pragma unroll
            for (int pxg = 0; pxg < 4; pxg++) {
                bf16x8 pf = *(const bf16x8*)(base + (pxg * 16 + l15) * C_IN);
                acc[pxg][0] = __builtin_amdgcn_mfma_f32_16x16x32_bf16(pf, w0, acc[pxg][0], 0, 0, 0);
                acc[pxg][1] = __builtin_amdgcn_mfma_f32_16x16x32_bf16(pf, w1, acc[pxg][1], 0, 0, 0);
            }
        }
    }

    // ---- bias prefetch for phase 0 (row y); latency hides under epilogue setup ----
    const size_t OHW = (size_t)OH * OW;
    const size_t obase = (size_t)(d0 + wave * 4) * OHW + (size_t)y * OW + x0 + lane * 4;
    f32x2 bp[4][2];
#pragma unroll
    for (int i = 0; i < 4; i++) {
        bp[i][0] = *(const f32x2*)&bias[obase + (size_t)i * OHW];
        bp[i][1] = *(const f32x2*)&bias[obase + (size_t)i * OHW + 2];
    }
#pragma unroll
    for (int i = 0; i < 4; i++) asm volatile("" : "+v"(bp[i][0]), "+v"(bp[i][1]));

    __syncthreads();                        // all lw reads done; lo may overwrite

    // ---- phase 0: row y. wr==0 waves dump acc, everyone stores 4 d-rows ----
    if (wr == 0) {
#pragma unroll
        for (int pxg = 0; pxg < 4; pxg++)
#pragma unroll
            for (int dg = 0; dg < 2; dg++)
                *(f32x4*)&lo[(dg * 16 + l15) * LO_STRIDE + wp * 64 + pxg * 16 + quad * 4] = acc[pxg][dg];
    }
    __syncthreads();

    // prefetch phase-1 bias while phase-0 reads/stores run (unpinned: compiler
    // may sink under register pressure, keeps VGPR <= the 512,6 budget)
    f32x2 bn[4][2];
#pragma unroll
    for (int i = 0; i < 4; i++) {
        bn[i][0] = *(const f32x2*)&bias[obase + (size_t)i * OHW + OW];
        bn[i][1] = *(const f32x2*)&bias[obase + (size_t)i * OHW + OW + 2];
    }

#pragma unroll
    for (int i = 0; i < 4; i++) {
        f32x4 v = *(const f32x4*)&lo[(wave * 4 + i) * LO_STRIDE + lane * 4];
        const size_t o = obase + (size_t)i * OHW;
        // f32x2: (y*510 + x0) can be ≡2 mod 4, so 16B stores would misalign
        f32x2 r0 = { v[0] + bp[i][0][0], v[1] + bp[i][0][1] };
        f32x2 r1 = { v[2] + bp[i][1][0], v[3] + bp[i][1][1] };
        *(f32x2*)&out[o]     = r0;
        *(f32x2*)&out[o + 2] = r1;
    }
    __syncthreads();                        // phase-0 lo reads done before overwrite

    // ---- phase 1: row y+1 ----
    if (wr == 1) {
#pragma unroll
        for (int pxg = 0; pxg < 4; pxg++)
#pragma unroll
            for (int dg = 0; dg < 2; dg++)
                *(f32x4*)&lo[(dg * 16 + l15) * LO_STRIDE + wp * 64 + pxg * 16 + quad * 4] = acc[pxg][dg];
    }
    __syncthreads();

#pragma unroll
    for (int i = 0; i < 4; i++) {
        f32x4 v = *(const f32x4*)&lo[(wave * 4 + i) * LO_STRIDE + lane * 4];
        const size_t o = obase + (size_t)i * OHW + OW;
        f32x2 r0 = { v[0] + bn[i][0][0], v[1] + bn[i][0][1] };
        f32x2 r1 = { v[2] + bn[i][1][0], v[3] + bn[i][1][1] };
        *(f32x2*)&out[o]     = r0;
        *(f32x2*)&out[o + 2] = r1;
    }
}

// ---------- fallback (proven v1) if workspace is too small ----------
#define PXT 64
#define TCOL 66
#define TCPAD 72

__global__ __launch_bounds__(256, 4)
void conv_bias_fallback(const float* __restrict__ in, const __bf16* __restrict__ wt,
                        const float* __restrict__ bias, float* __restrict__ out) {
    __shared__ __bf16 tile[3 * TCOL * TCPAD];
    const int b  = blockIdx.x;
    const int y  = b >> 3;
    const int x0 = (b & 7) * PXT;
    const int tid = threadIdx.x;
    for (int idx = tid; idx < 3 * TCOL * C_IN; idx += 256) {
        int col = idx % TCOL;
        int t   = idx / TCOL;
        int r   = t % 3;
        int c   = t / 3;
        int gx  = x0 + col;
        if (gx > W_IN - 1) gx = W_IN - 1;
        tile[(r * TCOL + col) * TCPAD + c] = (__bf16)in[(c * H_IN + (y + r)) * W_IN + gx];
    }
    __syncthreads();
    const int wave = tid >> 6, lane = tid & 63;
    const int l15 = lane & 15, quad = lane >> 4;
    const int px_base = wave * 16;
    f32x4 acc[8];
#pragma unroll
    for (int i = 0; i < 8; i++) acc[i] = (f32x4){0.f, 0.f, 0.f, 0.f};
#pragma unroll
    for (int kpos = 0; kpos < 9; kpos++) {
        const int ky = kpos / 3, kx = kpos % 3;
#pragma unroll
        for (int ch = 0; ch < 2; ch++) {
            const int c0 = ch * 32;
            bf16x8 bfrag = *(const bf16x8*)&tile[(ky * TCOL + px_base + l15 + kx) * TCPAD + c0 + quad * 8];
            const __bf16* aptr = wt + (size_t)kpos * D_OUT * C_IN + l15 * C_IN + c0 + quad * 8;
#pragma unroll
            for (int ds = 0; ds < 8; ds++) {
                bf16x8 afrag = *(const bf16x8*)(aptr + ds * 16 * C_IN);
                acc[ds] = __builtin_amdgcn_mfma_f32_16x16x32_bf16(afrag, bfrag, acc[ds], 0, 0, 0);
            }
        }
    }
    const int gx = x0 + px_base + l15;
    if (gx < OW) {
#pragma unroll
        for (int ds = 0; ds < 8; ds++) {
            const int dbase = ds * 16 + quad * 4;
#pragma unroll
            for (int r = 0; r < 4; r++) {
                const size_t o = ((size_t)(dbase + r) * OH + y) * OW + gx;
                out[o] = acc[ds][r] + bias[o];
            }
        }
    }
}

extern "C" void kernel_launch(void* const* d_in, const int* in_sizes, int n_in,
                              void* d_out, int out_size, void* d_ws, size_t ws_size,
                              hipStream_t stream) {
    const float* in   = (const float*)d_in[0];
    const float* w    = (const float*)d_in[1];
    const float* bias = (const float*)d_in[2];
    float* out = (float*)d_out;

    if (ws_size >= WS_NEEDED) {
        __bf16* tin = (__bf16*)d_ws;
        __bf16* wt  = (__bf16*)((char*)d_ws + TIN_BYTES);
        prep_weights<<<(9 * D_OUT * C_IN + 255) / 256, 256, 0, stream>>>(w, wt);
        transpose_in<<<H_IN * 4, 256, 0, stream>>>(in, tin);
        conv_main<<<(OH / 2) * 8, 512, 0, stream>>>(tin, wt, bias, out);
    } else {
        __bf16* wt = (__bf16*)d_ws;
        prep_weights<<<(9 * D_OUT * C_IN + 255) / 256, 256, 0, stream>>>(w, wt);
        conv_bias_fallback<<<OH * 8, 256, 0, stream>>>(in, wt, bias, out);
    }
}

// Round 3
// 410.961 us; speedup vs baseline: 1.0193x; 1.0193x over previous
//
#include <hip/hip_runtime.h>
#include <hip/hip_bf16.h>

#define C_IN 64
#define H_IN 512
#define W_IN 512
#define D_OUT 128
#define OH 510
#define OW 510

typedef __bf16 bf16x8 __attribute__((ext_vector_type(8)));
typedef float  f32x4  __attribute__((ext_vector_type(4)));
typedef float  f32x2  __attribute__((ext_vector_type(2)));

#define TIN_ELEMS (H_IN * W_IN * C_IN)
#define TIN_BYTES ((size_t)TIN_ELEMS * 2)        // 32 MB
#define WT_BYTES  (9 * D_OUT * C_IN * 2)         // 147,456
#define WS_NEEDED (TIN_BYTES + WT_BYTES)

// ---------- pre-pass: kernels [D][C][3][3] fp32 -> wt[kpos][d][c] bf16 ----------
__global__ void prep_weights(const float* __restrict__ w, __bf16* __restrict__ wt) {
    int i = blockIdx.x * blockDim.x + threadIdx.x;
    if (i >= 9 * D_OUT * C_IN) return;
    int c    = i & 63;
    int d    = (i >> 6) & 127;
    int kpos = i >> 13;
    wt[i] = (__bf16)w[((d * C_IN) + c) * 9 + kpos];
}

// ---------- pre-pass: input [c][y][x] fp32 -> tin[y][x][c] bf16 ----------
// Round 3 rewrite: barrier-free. Old version (LDS round-trip, 2 barriers,
// 4 blocks/CU) was latency-bound at ~0.5 TB/s. Now: block = 64 px x all 64 c;
// wave w handles c = w*16..w*16+15. Loads: lanes contiguous in px -> 256 B
// coalesced segments, 16 issued back-to-back per thread (deep MLP, no barrier).
// Stores: two bf16x8 per thread; the block completes 64 full 128-B tin lines
// on a single XCD so L2 write-combines them (no partial-line HBM writes).
__global__ __launch_bounds__(256, 8)
void transpose_in(const float* __restrict__ in, __bf16* __restrict__ tin) {
    const int t  = threadIdx.x;
    const int w  = t >> 6;                  // c-16-group 0..3
    const int l  = t & 63;
    const int px = blockIdx.x * 64 + l;     // linear y*512+x, 0..262143
    const float* src = in + (size_t)(w * 16) * (H_IN * W_IN) + px;
    float f[16];
#pragma unroll
    for (int j = 0; j < 16; j++) f[j] = src[(size_t)j * (H_IN * W_IN)];
    bf16x8 v0, v1;
#pragma unroll
    for (int j = 0; j < 8; j++) { v0[j] = (__bf16)f[j]; v1[j] = (__bf16)f[8 + j]; }
    __bf16* dst = tin + (size_t)px * C_IN + w * 16;
    *(bf16x8*)dst       = v0;
    *(bf16x8*)(dst + 8) = v1;
}

// ---------- main conv v5: explicit depth-2 load pipeline ----------
// v4 post-mortem: occupancy 42->59% and FETCH halved but dur flat at ~200 us.
// Invariant across v3/v4: ~10 loads in flight per CU (1.17M tin loads, 107
// cyc/load/CU) -> per-wave MLP bound, caused by VGPR=40 (launch_bounds 512,6):
// compiler had no registers to prefetch, so each group is load->drain->MFMA.
// Fix: 3-buffer ping-pong over 18 (kpos,ch) batches of 4 loads, lookahead 2
// (8 outstanding per wave), all buffer indices compile-time constants.
// launch_bounds(512,4): ~128-reg budget, 2 blocks/CU (16 waves) — trade a bit
// of occupancy for ~13x the per-wave MLP.
#define BPX 256
#define LO_STRIDE 260                        // dwords; 16B-aligned rows, bank-spread

#define LOADB(buf, kpos_, ch_)                                                    \
  { const int ky_ = (kpos_) / 3, kx_ = (kpos_) % 3;                               \
    const __bf16* base_ = tb + ((size_t)ky_ * W_IN + kx_) * C_IN + (ch_) * 32;    \
    buf[0] = *(const bf16x8*)(base_ + ( 0 + l15) * C_IN);                         \
    buf[1] = *(const bf16x8*)(base_ + (16 + l15) * C_IN);                         \
    buf[2] = *(const bf16x8*)(base_ + (32 + l15) * C_IN);                         \
    buf[3] = *(const bf16x8*)(base_ + (48 + l15) * C_IN); }

#define MFMAB(buf, kpos_, ch_)                                                    \
  { const int us_ = (((ch_) * 4 + quad) ^ (l15 & 7)) * 8;                         \
    bf16x8 w0_ = *(const bf16x8*)&lw[((kpos_) * 32      + l15) * 64 + us_];       \
    bf16x8 w1_ = *(const bf16x8*)&lw[((kpos_) * 32 + 16 + l15) * 64 + us_];       \
    acc[0][0] = __builtin_amdgcn_mfma_f32_16x16x32_bf16(buf[0], w0_, acc[0][0], 0, 0, 0); \
    acc[0][1] = __builtin_amdgcn_mfma_f32_16x16x32_bf16(buf[0], w1_, acc[0][1], 0, 0, 0); \
    acc[1][0] = __builtin_amdgcn_mfma_f32_16x16x32_bf16(buf[1], w0_, acc[1][0], 0, 0, 0); \
    acc[1][1] = __builtin_amdgcn_mfma_f32_16x16x32_bf16(buf[1], w1_, acc[1][1], 0, 0, 0); \
    acc[2][0] = __builtin_amdgcn_mfma_f32_16x16x32_bf16(buf[2], w0_, acc[2][0], 0, 0, 0); \
    acc[2][1] = __builtin_amdgcn_mfma_f32_16x16x32_bf16(buf[2], w1_, acc[2][1], 0, 0, 0); \
    acc[3][0] = __builtin_amdgcn_mfma_f32_16x16x32_bf16(buf[3], w0_, acc[3][0], 0, 0, 0); \
    acc[3][1] = __builtin_amdgcn_mfma_f32_16x16x32_bf16(buf[3], w1_, acc[3][1], 0, 0, 0); }

__global__ __launch_bounds__(512, 4)
void conv_main(const __bf16* __restrict__ tin, const __bf16* __restrict__ wt,
               const float* __restrict__ bias, float* __restrict__ out) {
    __shared__ __align__(16) char smem[9 * 32 * 64 * 2];   // 36,864 B
    __bf16* lw = (__bf16*)smem;              // [9][32][64] bf16, swizzled
    float*  lo = (float*)smem;               // [32][260] f32 after main loop

    // XCD-chunked swizzle: bid%8 picks the XCD (round-robin dispatch), so give
    // each XCD one contiguous y2 chunk. 2040/8 = 255 exactly -> bijective.
    const int bid = blockIdx.x;
    const int swz = (bid & 7) * 255 + (bid >> 3);
    const int dt  = swz & 3;
    const int xt  = (swz >> 2) & 1;
    const int y   = (swz >> 3) << 1;         // 0,2,...,508
    const int d0  = dt << 5;
    const int x0  = xt ? (OW - BPX) : 0;     // 0 or 254 (overlap px recomputed, same values)

    const int t    = threadIdx.x;
    const int wave = t >> 6;                 // 0..7
    const int lane = t & 63;
    const int l15  = lane & 15;
    const int quad = lane >> 4;
    const int wr   = wave >> 2;              // row within block (0/1)
    const int wp   = wave & 3;               // 64-px group within row

    // ---- stage this block's 32-d weight slice into LDS (once, all 9 kpos) ----
    for (int u = t; u < 9 * 32 * 8; u += 512) {
        const int kpos = u >> 8;
        const int r    = u & 255;
        const int dl   = r >> 3;
        const int oc   = r & 7;
        const int ocs  = (oc ^ (dl & 7)) * 8;   // XOR-swizzle 16B units within row
        bf16x8 v = *(const bf16x8*)(wt + kpos * (D_OUT * C_IN) + (d0 + dl) * C_IN + oc * 8);
        *(bf16x8*)&lw[(kpos * 32 + dl) * 64 + ocs] = v;
    }
    __syncthreads();

    f32x4 acc[4][2];
#pragma unroll
    for (int pxg = 0; pxg < 4; pxg++)
#pragma unroll
        for (int dg = 0; dg < 2; dg++)
            acc[pxg][dg] = (f32x4){0.f, 0.f, 0.f, 0.f};

    const __bf16* tb = tin + ((size_t)(y + wr) * W_IN + x0 + wp * 64) * C_IN + quad * 8;

    // ---- pipelined main loop: batch b = (kpos = b>>1, ch = b&1), lookahead 2 ----
    bf16x8 pbuf[3][4];
    LOADB(pbuf[0], 0, 0);
    LOADB(pbuf[1], 0, 1);
#pragma unroll
    for (int b2 = 0; b2 < 18; ++b2) {
        if (b2 < 16) LOADB(pbuf[(b2 + 2) % 3], (b2 + 2) >> 1, (b2 + 2) & 1);
        MFMAB(pbuf[b2 % 3], b2 >> 1, b2 & 1);
    }

    // ---- bias prefetch for phase 0 (row y) ----
    const size_t OHW = (size_t)OH * OW;
    const size_t obase = (size_t)(d0 + wave * 4) * OHW + (size_t)y * OW + x0 + lane * 4;
    f32x2 bp[4][2];
#pragma unroll
    for (int i = 0; i < 4; i++) {
        bp[i][0] = *(const f32x2*)&bias[obase + (size_t)i * OHW];
        bp[i][1] = *(const f32x2*)&bias[obase + (size_t)i * OHW + 2];
    }
#pragma unroll
    for (int i = 0; i < 4; i++) asm volatile("" : "+v"(bp[i][0]), "+v"(bp[i][1]));

    __syncthreads();                        // all lw reads done; lo may overwrite

    // ---- phase 0: row y ----
    if (wr == 0) {
#pragma unroll
        for (int pxg = 0; pxg < 4; pxg++)
#pragma unroll
            for (int dg = 0; dg < 2; dg++)
                *(f32x4*)&lo[(dg * 16 + l15) * LO_STRIDE + wp * 64 + pxg * 16 + quad * 4] = acc[pxg][dg];
    }
    __syncthreads();

    // prefetch phase-1 bias while phase-0 reads/stores run
    f32x2 bn[4][2];
#pragma unroll
    for (int i = 0; i < 4; i++) {
        bn[i][0] = *(const f32x2*)&bias[obase + (size_t)i * OHW + OW];
        bn[i][1] = *(const f32x2*)&bias[obase + (size_t)i * OHW + OW + 2];
    }

#pragma unroll
    for (int i = 0; i < 4; i++) {
        f32x4 v = *(const f32x4*)&lo[(wave * 4 + i) * LO_STRIDE + lane * 4];
        const size_t o = obase + (size_t)i * OHW;
        // f32x2: (y*510 + x0) can be ≡2 mod 4, so 16B stores would misalign
        f32x2 r0 = { v[0] + bp[i][0][0], v[1] + bp[i][0][1] };
        f32x2 r1 = { v[2] + bp[i][1][0], v[3] + bp[i][1][1] };
        *(f32x2*)&out[o]     = r0;
        *(f32x2*)&out[o + 2] = r1;
    }
    __syncthreads();                        // phase-0 lo reads done before overwrite

    // ---- phase 1: row y+1 ----
    if (wr == 1) {
#pragma unroll
        for (int pxg = 0; pxg < 4; pxg++)
#pragma unroll
            for (int dg = 0; dg < 2; dg++)
                *(f32x4*)&lo[(dg * 16 + l15) * LO_STRIDE + wp * 64 + pxg * 16 + quad * 4] = acc[pxg][dg];
    }
    __syncthreads();

#pragma unroll
    for (int i = 0; i < 4; i++) {
        f32x4 v = *(const f32x4*)&lo[(wave * 4 + i) * LO_STRIDE + lane * 4];
        const size_t o = obase + (size_t)i * OHW + OW;
        f32x2 r0 = { v[0] + bn[i][0][0], v[1] + bn[i][0][1] };
        f32x2 r1 = { v[2] + bn[i][1][0], v[3] + bn[i][1][1] };
        *(f32x2*)&out[o]     = r0;
        *(f32x2*)&out[o + 2] = r1;
    }
}

// ---------- fallback (proven v1) if workspace is too small ----------
#define PXT 64
#define TCOL 66
#define TCPAD 72

__global__ __launch_bounds__(256, 4)
void conv_bias_fallback(const float* __restrict__ in, const __bf16* __restrict__ wt,
                        const float* __restrict__ bias, float* __restrict__ out) {
    __shared__ __bf16 tile[3 * TCOL * TCPAD];
    const int b  = blockIdx.x;
    const int y  = b >> 3;
    const int x0 = (b & 7) * PXT;
    const int tid = threadIdx.x;
    for (int idx = tid; idx < 3 * TCOL * C_IN; idx += 256) {
        int col = idx % TCOL;
        int t   = idx / TCOL;
        int r   = t % 3;
        int c   = t / 3;
        int gx  = x0 + col;
        if (gx > W_IN - 1) gx = W_IN - 1;
        tile[(r * TCOL + col) * TCPAD + c] = (__bf16)in[(c * H_IN + (y + r)) * W_IN + gx];
    }
    __syncthreads();
    const int wave = tid >> 6, lane = tid & 63;
    const int l15 = lane & 15, quad = lane >> 4;
    const int px_base = wave * 16;
    f32x4 acc[8];
#pragma unroll
    for (int i = 0; i < 8; i++) acc[i] = (f32x4){0.f, 0.f, 0.f, 0.f};
#pragma unroll
    for (int kpos = 0; kpos < 9; kpos++) {
        const int ky = kpos / 3, kx = kpos % 3;
#pragma unroll
        for (int ch = 0; ch < 2; ch++) {
            const int c0 = ch * 32;
            bf16x8 bfrag = *(const bf16x8*)&tile[(ky * TCOL + px_base + l15 + kx) * TCPAD + c0 + quad * 8];
            const __bf16* aptr = wt + (size_t)kpos * D_OUT * C_IN + l15 * C_IN + c0 + quad * 8;
#pragma unroll
            for (int ds = 0; ds < 8; ds++) {
                bf16x8 afrag = *(const bf16x8*)(aptr + ds * 16 * C_IN);
                acc[ds] = __builtin_amdgcn_mfma_f32_16x16x32_bf16(afrag, bfrag, acc[ds], 0, 0, 0);
            }
        }
    }
    const int gx = x0 + px_base + l15;
    if (gx < OW) {
#pragma unroll
        for (int ds = 0; ds < 8; ds++) {
            const int dbase = ds * 16 + quad * 4;
#pragma unroll
            for (int r = 0; r < 4; r++) {
                const size_t o = ((size_t)(dbase + r) * OH + y) * OW + gx;
                out[o] = acc[ds][r] + bias[o];
            }
        }
    }
}

extern "C" void kernel_launch(void* const* d_in, const int* in_sizes, int n_in,
                              void* d_out, int out_size, void* d_ws, size_t ws_size,
                              hipStream_t stream) {
    const float* in   = (const float*)d_in[0];
    const float* w    = (const float*)d_in[1];
    const float* bias = (const float*)d_in[2];
    float* out = (float*)d_out;

    if (ws_size >= WS_NEEDED) {
        __bf16* tin = (__bf16*)d_ws;
        __bf16* wt  = (__bf16*)((char*)d_ws + TIN_BYTES);
        prep_weights<<<(9 * D_OUT * C_IN + 255) / 256, 256, 0, stream>>>(w, wt);
        transpose_in<<<(H_IN * W_IN) / 64, 256, 0, stream>>>(in, tin);
        conv_main<<<(OH / 2) * 8, 512, 0, stream>>>(tin, wt, bias, out);
    } else {
        __bf16* wt = (__bf16*)d_ws;
        prep_weights<<<(9 * D_OUT * C_IN + 255) / 256, 256, 0, stream>>>(w, wt);
        conv_bias_fallback<<<OH * 8, 256, 0, stream>>>(in, wt, bias, out);
    }
}